// Round 1
// baseline (397.208 us; speedup 1.0000x reference)
//
#include <hip/hip_runtime.h>
#include <hip/hip_bf16.h>

#define B_ 8
#define D_ 40
#define T_ 192
#define G_ 256
#define U_ 768   // 3*UNITS
#define H_ 256   // UNITS

typedef _Float16 half2_t __attribute__((ext_vector_type(2)));

__device__ inline float fdot2f(half2_t a, half2_t b, float c){
#if __has_builtin(__builtin_amdgcn_fdot2)
  return __builtin_amdgcn_fdot2(a, b, c, false);
#else
  return c + (float)a.x*(float)b.x + (float)a.y*(float)b.y;
#endif
}

__device__ inline float sigmoidf_(float x){
  return 1.0f/(1.0f+__expf(-x));
}
__device__ inline float tanhf_(float x){
  // stable: tanh(x) = sign(x)*(1-e)/(1+e), e=exp(-2|x|)
  float ax = fabsf(x);
  float e = __expf(-2.0f*ax);
  float t = (1.0f-e)/(1.0f+e);
  return copysignf(t, x);
}

// ---------------- Kernel 1: single-channel interp + per-(b,d) mean ----------
__global__ __launch_bounds__(256) void k_interp(
    const float* __restrict__ times, const float* __restrict__ values,
    const float* __restrict__ meas, const float* __restrict__ grid,
    const float* __restrict__ ksic,
    float* __restrict__ y, float* __restrict__ w, float* __restrict__ ytr,
    float* __restrict__ mean){
  int bd = blockIdx.x;            // b*D_+d
  int b = bd / D_, d = bd % D_;
  int g = threadIdx.x;
  __shared__ float tt[T_], vv[T_], mm[T_];
  __shared__ float red[256];
  if (g < T_){
    tt[g] = times[bd*T_+g];
    vv[g] = values[bd*T_+g];
    mm[g] = meas[bd*T_+g];
  }
  __syncthreads();
  float alpha = log1pf(__expf(ksic[d]));   // softplus
  float tg = grid[b*G_+g];
  // pass 1: min over observed of norm
  float nmin = 3.4e38f;
  for (int t=0;t<T_;t++){
    if (mm[t] > 0.0f){                      // uniform branch (mask shared across block)
      float dd = tt[t]-tg;
      nmin = fminf(nmin, dd*dd);
    }
  }
  // pass 2: accumulate both scales (same max location since argmin shared)
  float s1=0.f, sv1=0.f, s10=0.f, sv10=0.f;
  for (int t=0;t<T_;t++){
    if (mm[t] > 0.0f){
      float dd = tt[t]-tg;
      float n = dd*dd - nmin;               // >= 0
      float e1  = __expf(-alpha*n);
      float e10 = __expf(-10.0f*alpha*n);
      s1 += e1;  sv1 += e1*vv[t];
      s10 += e10; sv10 += e10*vv[t];
    }
  }
  float yv = sv1/s1;
  float wv = -alpha*nmin + __logf(s1);
  y[bd*G_+g]   = yv;
  w[bd*G_+g]   = wv;
  ytr[bd*G_+g] = sv10/s10;
  // mean over g (all G, not grid_lengths)
  red[g] = yv;
  __syncthreads();
  for (int s=128;s>0;s>>=1){
    if (g<s) red[g]+=red[g+s];
    __syncthreads();
  }
  if (g==0) mean[bd] = red[0]*(1.0f/(float)G_);
}

// ---------------- Kernel 2: cross-channel interp + feats + x_proj -----------
__global__ __launch_bounds__(256) void k_cross(
    const float* __restrict__ y, const float* __restrict__ w,
    const float* __restrict__ ytr, const float* __restrict__ mean,
    const float* __restrict__ crossW, const float* __restrict__ Wx,
    const float* __restrict__ gru_b, const int* __restrict__ lens,
    float* __restrict__ xproj){
  int bg = blockIdx.x;              // b*G_+g
  int b = bg >> 8, g = bg & 255;
  if (g >= lens[b]) return;         // x_proj unused beyond length (uniform exit)
  __shared__ float wd[D_], yd[D_], ytrd[D_], md[D_], cc[D_], feats[3*D_];
  __shared__ float wstat[2];
  int tid = threadIdx.x;
  if (tid < D_){
    int idx = (b*D_+tid)*G_+g;
    wd[tid]=w[idx]; yd[tid]=y[idx]; ytrd[tid]=ytr[idx]; md[tid]=mean[b*D_+tid];
  }
  __syncthreads();
  if (tid==0){
    float mx=-3.4e38f;
    for (int d2=0;d2<D_;d2++) mx = fmaxf(mx, wd[d2]);
    float s=0.f;
    for (int d2=0;d2<D_;d2++) s += __expf(wd[d2]-mx);
    wstat[0]=mx; wstat[1]=1.0f/s;
  }
  __syncthreads();
  if (tid<D_){
    float sw = __expf(wd[tid]-wstat[0])*wstat[1];
    cc[tid] = sw*(yd[tid]-md[tid]);
  }
  __syncthreads();
  if (tid<D_){
    float acc=0.f;
    for (int d2=0;d2<D_;d2++) acc += cc[d2]*crossW[d2*D_+tid];
    float rep = acc + md[tid];
    feats[tid]       = rep;                   // rep1
    feats[D_+tid]    = __expf(wd[tid]);       // intensity
    feats[2*D_+tid]  = ytrd[tid]-rep;         // y_trans - rep1
  }
  __syncthreads();
  // x_proj[j] = feats . Wx[:,j] + bi[j]   (bi = gru_b row 0)
  for (int jj=0;jj<3;jj++){
    int j = tid + jj*256;
    float acc = gru_b[j];
    #pragma unroll 4
    for (int i=0;i<3*D_;i++) acc += feats[i]*Wx[i*U_+j];
    xproj[(size_t)bg*U_ + j] = acc;
  }
}

// ---------------- Kernel 3: demo MLP -> h0 ----------------------------------
__global__ __launch_bounds__(256) void k_demo(
    const float* __restrict__ demo, const float* __restrict__ W1,
    const float* __restrict__ b1, const float* __restrict__ W2,
    const float* __restrict__ b2, float* __restrict__ h0){
  __shared__ float dl[B_*16];
  __shared__ float hid[B_*H_];
  int u = threadIdx.x;
  if (u < B_*16) dl[u] = demo[u];
  __syncthreads();
  float acc[B_];
  #pragma unroll
  for (int b=0;b<B_;b++) acc[b]=b1[u];
  for (int i=0;i<16;i++){
    float w1 = W1[i*H_+u];
    #pragma unroll
    for (int b=0;b<B_;b++) acc[b] += dl[b*16+i]*w1;
  }
  #pragma unroll
  for (int b=0;b<B_;b++) hid[b*H_+u] = fmaxf(acc[b],0.f);
  __syncthreads();
  #pragma unroll
  for (int b=0;b<B_;b++) acc[b]=b2[u];
  for (int k=0;k<H_;k++){
    float w2 = W2[k*H_+u];
    #pragma unroll
    for (int b=0;b<B_;b++) acc[b] += hid[b*H_+k]*w2;
  }
  #pragma unroll
  for (int b=0;b<B_;b++) h0[b*H_+u]=acc[b];
}

// ---------------- Kernel 4: masked GRU (one block per batch) ----------------
// 768 threads: thread j owns column j of Wh (256 f32 -> 128 f16x2 in VGPRs).
// h kept in LDS (f32 for update, f16 for the dot). Early exit at lens[b]
// (mask is prefix-true so masked steps are identity).
__global__ __launch_bounds__(768,3) void k_gru(
    const float* __restrict__ Wh, const float* __restrict__ gru_b,
    const float* __restrict__ xproj, const float* __restrict__ h0,
    const int* __restrict__ lens, const float* __restrict__ outW,
    const float* __restrict__ outb, float* __restrict__ out){
  int b = blockIdx.x;
  int j = threadIdx.x;
  __shared__ half2_t hh2[H_/2];   // h as f16 pairs for dot
  __shared__ float hf[H_];        // h f32 state
  __shared__ float s[U_];         // gate pre-activations (z,r) and xh
  __shared__ float hpl[H_];       // hp for the candidate gate
  __shared__ float red[H_];

  // preload Wh column j into registers (f16 packed)
  half2_t wreg[H_/2];
  #pragma unroll
  for (int kk=0;kk<H_/2;kk++){
    float w0 = Wh[(2*kk)*U_+j];
    float w1 = Wh[(2*kk+1)*U_+j];
    half2_t h2; h2.x=(_Float16)w0; h2.y=(_Float16)w1;
    wreg[kk]=h2;
  }
  float brj = gru_b[U_+j];        // recurrent bias (row 1)
  if (j < H_){
    float h = h0[b*H_+j];
    hf[j]=h;
    ((_Float16*)hh2)[j] = (_Float16)h;
  }
  int len = lens[b];
  __syncthreads();

  for (int g=0; g<len; g++){
    float xp = xproj[((size_t)(b*G_+g))*U_ + j];
    float a0=brj, a1=0.f, a2=0.f, a3=0.f;
    #pragma unroll
    for (int kk=0;kk<H_/2;kk+=4){
      a0 = fdot2f(hh2[kk+0], wreg[kk+0], a0);
      a1 = fdot2f(hh2[kk+1], wreg[kk+1], a1);
      a2 = fdot2f(hh2[kk+2], wreg[kk+2], a2);
      a3 = fdot2f(hh2[kk+3], wreg[kk+3], a3);
    }
    float acc = (a0+a1)+(a2+a3);
    if (j < 2*H_) s[j] = xp + acc;        // z, r pre-activations
    else { s[j] = xp; hpl[j-2*H_] = acc; } // xh ; hh'
    __syncthreads();
    if (j < H_){
      float z = sigmoidf_(s[j]);
      float r = sigmoidf_(s[H_+j]);
      float cand = tanhf_(s[2*H_+j] + r*hpl[j]);
      float hn = z*hf[j] + (1.0f-z)*cand;
      hf[j]=hn;
      ((_Float16*)hh2)[j] = (_Float16)hn;
    }
    __syncthreads();
  }

  // out = sigmoid(h . outW + outb)
  if (j < H_) red[j] = hf[j]*outW[j];
  __syncthreads();
  for (int st=128;st>0;st>>=1){
    if (j<st) red[j]+=red[j+st];
    __syncthreads();
  }
  if (j==0) out[b] = sigmoidf_(red[0]+outb[0]);
}

extern "C" void kernel_launch(void* const* d_in, const int* in_sizes, int n_in,
                              void* d_out, int out_size, void* d_ws, size_t ws_size,
                              hipStream_t stream) {
  const float* demo   = (const float*)d_in[0];
  const float* times  = (const float*)d_in[1];
  const float* values = (const float*)d_in[2];
  const float* meas   = (const float*)d_in[3];
  const float* grid   = (const float*)d_in[4];
  const float* ksic   = (const float*)d_in[5];
  const float* crossW = (const float*)d_in[6];
  const float* dW1    = (const float*)d_in[7];
  const float* db1    = (const float*)d_in[8];
  const float* dW2    = (const float*)d_in[9];
  const float* db2    = (const float*)d_in[10];
  const float* gWx    = (const float*)d_in[11];
  const float* gWh    = (const float*)d_in[12];
  const float* gb     = (const float*)d_in[13];
  const float* outW   = (const float*)d_in[14];
  const float* outb   = (const float*)d_in[15];
  const int*   lens   = (const int*)d_in[16];
  float* out = (float*)d_out;

  // workspace layout (floats)
  float* ws   = (float*)d_ws;
  float* y    = ws;                        // B*D*G = 81920
  float* w    = y    + B_*D_*G_;           // 81920
  float* ytr  = w    + B_*D_*G_;           // 81920
  float* mean = ytr  + B_*D_*G_;           // 320
  float* h0   = mean + B_*D_;              // 2048
  float* xprj = h0   + B_*H_;              // B*G*768 = 1572864

  k_interp<<<B_*D_, 256, 0, stream>>>(times, values, meas, grid, ksic, y, w, ytr, mean);
  k_demo  <<<1,     256, 0, stream>>>(demo, dW1, db1, dW2, db2, h0);
  k_cross <<<B_*G_, 256, 0, stream>>>(y, w, ytr, mean, crossW, gWx, gb, lens, xprj);
  k_gru   <<<B_,    768, 0, stream>>>(gWh, gb, xprj, h0, lens, outW, outb, out);
}